// Round 1
// baseline (148.280 us; speedup 1.0000x reference)
//
#include <hip/hip_runtime.h>
#include <stdint.h>

#define B_  4
#define T_  2048
#define C_  1024
#define D_  64

typedef float  f32x4  __attribute__((ext_vector_type(4)));
typedef float  f32x16 __attribute__((ext_vector_type(16)));
typedef short  s16x8  __attribute__((ext_vector_type(8)));

// softmax scale folded into Q-side weights/bias: 1/sqrt(64) * log2(e)
#define QSCALE 0.18033688011112042f

static __device__ __forceinline__ uint32_t f2bf(float f) {
  uint32_t u = __builtin_bit_cast(uint32_t, f);
  u += 0x7FFFu + ((u >> 16) & 1u);   // round-to-nearest-even
  return u >> 16;
}
static __device__ __forceinline__ uint32_t pack2bf(float a, float b) {
  return f2bf(a) | (f2bf(b) << 16);
}
static __device__ __forceinline__ s16x8 pack8bf(float4 a, float4 b) {
  union { uint32_t u[4]; s16x8 v; } cv;
  cv.u[0] = pack2bf(a.x, a.y);
  cv.u[1] = pack2bf(a.z, a.w);
  cv.u[2] = pack2bf(b.x, b.y);
  cv.u[3] = pack2bf(b.z, b.w);
  return cv.v;
}

// ---------------------------------------------------------------------------
// Kernel 1: pack W{q,k,v} (fp32 [C,64]) -> WcatT bf16 [192][1024] (transposed,
// rows k-contiguous for MFMA A-operand), plus biascat[192]. Q part pre-scaled.
// ---------------------------------------------------------------------------
__global__ __launch_bounds__(256) void wconv_kernel(
    const float* __restrict__ Wq, const float* __restrict__ bq,
    const float* __restrict__ Wk, const float* __restrict__ bk,
    const float* __restrict__ Wv, const float* __restrict__ bv,
    uint16_t* __restrict__ WcatT, float* __restrict__ biascat) {
  const int n = blockIdx.x;      // 0..191
  const int tid = threadIdx.x;   // 0..255
  const float* W; int col; float s;
  if (n < 64)       { W = Wq; col = n;       s = QSCALE; }
  else if (n < 128) { W = Wk; col = n - 64;  s = 1.0f;   }
  else              { W = Wv; col = n - 128; s = 1.0f;   }
  const int c0 = tid * 4;
  float v0 = W[(size_t)(c0 + 0) * D_ + col] * s;
  float v1 = W[(size_t)(c0 + 1) * D_ + col] * s;
  float v2 = W[(size_t)(c0 + 2) * D_ + col] * s;
  float v3 = W[(size_t)(c0 + 3) * D_ + col] * s;
  uint2 st;
  st.x = pack2bf(v0, v1);
  st.y = pack2bf(v2, v3);
  *reinterpret_cast<uint2*>(WcatT + (size_t)n * C_ + c0) = st;
  if (n == 0 && tid < 192) {
    float bb;
    if (tid < 64)       bb = bq[tid] * QSCALE;
    else if (tid < 128) bb = bk[tid - 64];
    else                bb = bv[tid - 128];
    biascat[tid] = bb;
  }
}

// ---------------------------------------------------------------------------
// Kernel 2: QKV projection. OutT[n][m] = sum_c WcatT[n][c] * x[m][c] (+bias).
// 16x16x32 bf16 MFMA; A from global WcatT (L2), B = x rows fp32->bf16 inline.
// No barriers. Grid 256 blocks x 32 rows; 4 waves split the 192 n-columns.
// Outputs: Qbf/Kbf bf16 [8192][64] row-major, Vt bf16 [4][64][2048].
// ---------------------------------------------------------------------------
__global__ __launch_bounds__(256) void proj_kernel(
    const float* __restrict__ x, const uint16_t* __restrict__ WcatT,
    const float* __restrict__ biascat,
    uint16_t* __restrict__ Qbf, uint16_t* __restrict__ Kbf,
    uint16_t* __restrict__ Vt) {
  __shared__ __align__(16) uint16_t tbuf[4][32 * 24];
  const int tid  = threadIdx.x;
  const int wave = tid >> 6;
  const int lane = tid & 63;
  const int mrow = lane & 15;   // row within 16-tile (B-frag n-index / A-frag m-index)
  const int u    = lane >> 4;   // k-group 0..3
  const int m0   = blockIdx.x * 32;

  const float*    xr0 = x + (size_t)(m0 + mrow) * C_ + u * 8;
  const float*    xr1 = xr0 + (size_t)16 * C_;
  const uint16_t* wb  = WcatT + (size_t)(wave * 48 + mrow) * C_ + u * 8;

  f32x4 acc[3][2];
#pragma unroll
  for (int i = 0; i < 3; ++i)
#pragma unroll
    for (int j = 0; j < 2; ++j)
#pragma unroll
      for (int r = 0; r < 4; ++r) acc[i][j][r] = 0.f;

  for (int s = 0; s < 32; ++s) {
    const int cb = s * 32;
    float4 a0 = *reinterpret_cast<const float4*>(xr0 + cb);
    float4 a1 = *reinterpret_cast<const float4*>(xr0 + cb + 4);
    float4 b0 = *reinterpret_cast<const float4*>(xr1 + cb);
    float4 b1 = *reinterpret_cast<const float4*>(xr1 + cb + 4);
    s16x8 xf0 = pack8bf(a0, a1);
    s16x8 xf1 = pack8bf(b0, b1);
#pragma unroll
    for (int nt = 0; nt < 3; ++nt) {
      s16x8 af = *reinterpret_cast<const s16x8*>(wb + (size_t)nt * 16 * C_ + cb);
      acc[nt][0] = __builtin_amdgcn_mfma_f32_16x16x32_bf16(af, xf0, acc[nt][0], 0, 0, 0);
      acc[nt][1] = __builtin_amdgcn_mfma_f32_16x16x32_bf16(af, xf1, acc[nt][1], 0, 0, 0);
    }
  }

  // epilogue: element (n = nb + u*4 + r, m = m0 + mt*16 + mrow)
  const int bb  = m0 >> 11;        // batch
  const int tt0 = m0 & (T_ - 1);   // t offset within batch
#pragma unroll
  for (int nt = 0; nt < 3; ++nt) {
    const int nb = wave * 48 + nt * 16;
    uint16_t vals[2][4];
#pragma unroll
    for (int mt = 0; mt < 2; ++mt)
#pragma unroll
      for (int r = 0; r < 4; ++r) {
        float v = acc[nt][mt][r] + biascat[nb + u * 4 + r];
        vals[mt][r] = (uint16_t)f2bf(v);
      }
    if (nb >= 128) {
      // V: store directly transposed (coalesced: m in lane%16)
#pragma unroll
      for (int mt = 0; mt < 2; ++mt)
#pragma unroll
        for (int r = 0; r < 4; ++r) {
          int vrow = nb - 128 + u * 4 + r;
          int t    = tt0 + mt * 16 + mrow;
          Vt[((size_t)bb * D_ + vrow) * T_ + t] = vals[mt][r];
        }
    } else {
      // Q/K: per-wave LDS transpose then coalesced 16B stores
#pragma unroll
      for (int mt = 0; mt < 2; ++mt)
#pragma unroll
        for (int r = 0; r < 4; ++r)
          tbuf[wave][(mt * 16 + mrow) * 24 + u * 4 + r] = vals[mt][r];
      const int mrd = lane >> 1, half = lane & 1;
      uint4 v = *reinterpret_cast<const uint4*>(&tbuf[wave][mrd * 24 + half * 8]);
      uint16_t* dst = (nb < 64) ? (Qbf + nb) : (Kbf + (nb - 64));
      *reinterpret_cast<uint4*>(dst + (size_t)(m0 + mrd) * D_ + half * 8) = v;
    }
  }
}

// ---------------------------------------------------------------------------
// Kernel 3: causal attention, flash-style without online max (logits bounded:
// scale*log2e folded into Q, |s| < ~30 so exp2 is safe and self-normalizing).
// S^T = K.Q^T and O^T = V^T.P^T via 32x32x16 bf16 MFMA: all operands
// contiguous from global (K rows, Q rows, Vt rows); only P round-trips LDS.
// 4 waves k-split (stride 4) one 32-row q-tile; no barriers in the k-loop.
// ---------------------------------------------------------------------------
__global__ __launch_bounds__(256) void attn_kernel(
    const uint16_t* __restrict__ Qbf, const uint16_t* __restrict__ Kbf,
    const uint16_t* __restrict__ Vt, float* __restrict__ out) {
  __shared__ __align__(16) uint16_t plds[4][32 * 40];  // per-wave P, pitch 40
  __shared__ float obuf[64 * 33];
  __shared__ float lbuf[32];

  const int tid  = threadIdx.x;
  const int wave = tid >> 6;
  const int lane = tid & 63;
  const int ql   = lane & 31;  // q-index (MFMA N / col), also k-row & d-row for A-frags
  const int hi   = lane >> 5;

  // swizzle: batch pinned to an XCD pair for K/V L2 locality
  const int blk = blockIdx.x;
  const int b   = (blk & 7) >> 1;
  const int qt  = 2 * (blk >> 3) + (blk & 1);  // 0..63
  const int qb  = qt * 32;

  const uint16_t* Qb = Qbf + (size_t)b * T_ * D_;
  const uint16_t* Kb = Kbf + (size_t)b * T_ * D_;
  const uint16_t* Vb = Vt + (size_t)b * D_ * T_;

  s16x8 qf[4];
#pragma unroll
  for (int c = 0; c < 4; ++c)
    qf[c] = *reinterpret_cast<const s16x8*>(Qb + (size_t)(qb + ql) * D_ + c * 16 + hi * 8);

  f32x16 aco[2];
#pragma unroll
  for (int i = 0; i < 2; ++i)
#pragma unroll
    for (int r = 0; r < 16; ++r) aco[i][r] = 0.f;
  float lacc = 0.f;

  for (int t = wave; t <= qt; t += 4) {
    const int kb = t * 32;
    f32x16 sacc;
#pragma unroll
    for (int r = 0; r < 16; ++r) sacc[r] = 0.f;
#pragma unroll
    for (int c = 0; c < 4; ++c) {
      s16x8 kf = *reinterpret_cast<const s16x8*>(Kb + (size_t)(kb + ql) * D_ + c * 16 + hi * 8);
      sacc = __builtin_amdgcn_mfma_f32_32x32x16_bf16(kf, qf[c], sacc, 0, 0, 0);
    }
    if (t == qt) {  // diagonal tile: causal mask (k > q -> -inf)
#pragma unroll
      for (int r = 0; r < 16; ++r) {
        const int koff = (r & 3) + 8 * (r >> 2) + 4 * hi;
        sacc[r] = (koff > ql) ? -1e30f : sacc[r];
      }
    }
    float p[16];
#pragma unroll
    for (int r = 0; r < 16; ++r) p[r] = __builtin_amdgcn_exp2f(sacc[r]);
    float s01 = (p[0] + p[1]) + (p[2] + p[3]);
    float s23 = (p[4] + p[5]) + (p[6] + p[7]);
    float s45 = (p[8] + p[9]) + (p[10] + p[11]);
    float s67 = (p[12] + p[13]) + (p[14] + p[15]);
    lacc += (s01 + s23) + (s45 + s67);
    // P (C-layout) -> A-usable layout via per-wave LDS; regs 4g..4g+3 are
    // k = 8g + 4*hi + {0..3} at fixed q
#pragma unroll
    for (int g = 0; g < 4; ++g) {
      uint2 w;
      w.x = pack2bf(p[4 * g + 0], p[4 * g + 1]);
      w.y = pack2bf(p[4 * g + 2], p[4 * g + 3]);
      *reinterpret_cast<uint2*>(&plds[wave][ql * 40 + 8 * g + 4 * hi]) = w;
    }
#pragma unroll
    for (int kc = 0; kc < 2; ++kc) {
      s16x8 pf = *reinterpret_cast<const s16x8*>(&plds[wave][ql * 40 + kc * 16 + hi * 8]);
#pragma unroll
      for (int dm = 0; dm < 2; ++dm) {
        s16x8 vf = *reinterpret_cast<const s16x8*>(
            Vb + (size_t)(dm * 32 + ql) * T_ + kb + kc * 16 + hi * 8);
        aco[dm] = __builtin_amdgcn_mfma_f32_32x32x16_bf16(vf, pf, aco[dm], 0, 0, 0);
      }
    }
  }

  lacc += __shfl_xor(lacc, 32, 64);

  for (int i = tid; i < 64 * 33; i += 256) obuf[i] = 0.f;
  if (tid < 32) lbuf[tid] = 0.f;
  __syncthreads();

  if (hi == 0) atomicAdd(&lbuf[ql], lacc);
#pragma unroll
  for (int dm = 0; dm < 2; ++dm)
#pragma unroll
    for (int r = 0; r < 16; ++r) {
      const int d = dm * 32 + (r & 3) + 8 * (r >> 2) + 4 * hi;
      atomicAdd(&obuf[d * 33 + ql], aco[dm][r]);
    }
  __syncthreads();

  const int q  = tid >> 3;
  const int dg = (tid & 7) * 8;
  const float rinv = 1.0f / lbuf[q];
  float4 o0, o1;
  o0.x = obuf[(dg + 0) * 33 + q] * rinv;
  o0.y = obuf[(dg + 1) * 33 + q] * rinv;
  o0.z = obuf[(dg + 2) * 33 + q] * rinv;
  o0.w = obuf[(dg + 3) * 33 + q] * rinv;
  o1.x = obuf[(dg + 4) * 33 + q] * rinv;
  o1.y = obuf[(dg + 5) * 33 + q] * rinv;
  o1.z = obuf[(dg + 6) * 33 + q] * rinv;
  o1.w = obuf[(dg + 7) * 33 + q] * rinv;
  float* op = out + ((size_t)(b * T_ + qb + q)) * D_ + dg;
  *reinterpret_cast<float4*>(op)     = o0;
  *reinterpret_cast<float4*>(op + 4) = o1;
}

// ---------------------------------------------------------------------------
extern "C" void kernel_launch(void* const* d_in, const int* in_sizes, int n_in,
                              void* d_out, int out_size, void* d_ws, size_t ws_size,
                              hipStream_t stream) {
  (void)in_sizes; (void)n_in; (void)out_size; (void)ws_size;
  const float* x  = (const float*)d_in[0];
  const float* Wq = (const float*)d_in[1];
  const float* bq = (const float*)d_in[2];
  const float* Wk = (const float*)d_in[3];
  const float* bk = (const float*)d_in[4];
  const float* Wv = (const float*)d_in[5];
  const float* bv = (const float*)d_in[6];
  float* out = (float*)d_out;

  char* ws = (char*)d_ws;
  uint16_t* WcatT   = (uint16_t*)(ws);                 // 192*1024*2 = 393216
  float*    biascat = (float*)(ws + 393216);           // 768 (padded to 1024)
  uint16_t* Qbf     = (uint16_t*)(ws + 394240);        // 1048576
  uint16_t* Kbf     = (uint16_t*)(ws + 1442816);       // 1048576
  uint16_t* Vt      = (uint16_t*)(ws + 2491392);       // 1048576

  hipLaunchKernelGGL(wconv_kernel, dim3(192), dim3(256), 0, stream,
                     Wq, bq, Wk, bk, Wv, bv, WcatT, biascat);
  hipLaunchKernelGGL(proj_kernel, dim3(256), dim3(256), 0, stream,
                     x, WcatT, biascat, Qbf, Kbf, Vt);
  hipLaunchKernelGGL(attn_kernel, dim3(256), dim3(256), 0, stream,
                     Qbf, Kbf, Vt, out);
}